// Round 10
// baseline (313.055 us; speedup 1.0000x reference)
//
#include <hip/hip_runtime.h>
#include <hip/hip_bf16.h>
#include <math.h>

#define M_TOK 16384
#define N_EXP 256
#define K_DIM 7168
#define BK 32
#define KSTEPS (K_DIM / BK)  /* 224 */
#define KH (KSTEPS / 2)      /* 112 steps per K-half */
#define WTILE 32768          /* bytes per k-step W image: 16KB hi + 16KB lo (fp16) */
#define IMG_BYTES ((size_t)KSTEPS * WTILE)  /* 7.34 MB */
#define P_ELEMS ((size_t)M_TOK * N_EXP)
#define TOPK 8
#define SX 4096.0f
#define SW 16384.0f
#define DESCALE 1.4901161193847656e-08f /* 2^-26 */

typedef __attribute__((ext_vector_type(8))) _Float16 half8;
typedef __attribute__((ext_vector_type(4))) _Float16 half4;
typedef __attribute__((ext_vector_type(4))) float f32x4;

__device__ __forceinline__ void cvt8_2(const float* v, half8& h, half8& l) {
#pragma unroll
  for (int i = 0; i < 8; ++i) {
    _Float16 a = (_Float16)v[i];
    float r = v[i] - (float)a;
    h[i] = a;
    l[i] = (_Float16)r;
  }
}
__device__ __forceinline__ void cvt4_2(const float* v, half4& h, half4& l) {
#pragma unroll
  for (int i = 0; i < 4; ++i) {
    _Float16 a = (_Float16)v[i];
    float r = v[i] - (float)a;
    h[i] = a;
    l[i] = (_Float16)r;
  }
}

__device__ __forceinline__ unsigned long long pack_ci(float key, int idx) {
  unsigned int u = __builtin_bit_cast(unsigned int, key);
  u = (u & 0x80000000u) ? ~u : (u | 0x80000000u);
  return ((unsigned long long)u << 32) | (unsigned)(255 - idx);
}
__device__ __forceinline__ unsigned long long shflx64(unsigned long long v, int off) {
  int lo = __shfl_xor((int)(unsigned)(v & 0xffffffffull), off);
  int hi = __shfl_xor((int)(unsigned)(v >> 32), off);
  return ((unsigned long long)(unsigned)hi << 32) | (unsigned)lo;
}

// gate_weight fp32 [256][7168] -> per-kstep swizzled fp16 images in ws.
// Image t (32KB): hi plane [256 rows][64B] at +0, lo plane at +16384.
// byte col of 16B granule kc: (kc*16) ^ ((e&6)<<3).
__global__ void prep_w_kernel(const float* __restrict__ W, unsigned char* __restrict__ ws) {
  int t = blockIdx.x;
  int e = threadIdx.x;
  const float* src = W + (size_t)e * K_DIM + t * BK;
  unsigned char* dst = ws + (size_t)t * WTILE;
#pragma unroll
  for (int kc = 0; kc < 4; ++kc) {
    float v[8];
    float4 a = ((const float4*)src)[kc * 2];
    float4 b = ((const float4*)src)[kc * 2 + 1];
    v[0] = a.x * SW; v[1] = a.y * SW; v[2] = a.z * SW; v[3] = a.w * SW;
    v[4] = b.x * SW; v[5] = b.y * SW; v[6] = b.z * SW; v[7] = b.w * SW;
    half8 h, l;
    cvt8_2(v, h, l);
    int col = (kc * 16) ^ ((e & 6) << 3);
    *(half8*)(dst + e * 64 + col) = h;
    *(half8*)(dst + 16384 + e * 64 + col) = l;
  }
}

// ---------------------------------------------------------------------------
// K-split GEMM, A-only LDS, W direct global->reg.
// Grid 1024 = 512 M-tiles (BM=32) x 2 K-halves; 4 blocks/CU (8KB LDS each).
// khalf = (g>>2)&1 -> XCDs 0-3 serve khalf 0, XCDs 4-7 khalf 1 (L2 affinity).
// ---------------------------------------------------------------------------
__global__ __launch_bounds__(256, 4) void gate_split_kernel(
    const float* __restrict__ X,
    const unsigned char* __restrict__ ws,
    float* __restrict__ part) {
  // LDS: A dbuf [2][4KB]; buf b: hi plane [32 rows][64B] at b*4096, lo at +2048.
  __shared__ unsigned char smem[8192] __attribute__((aligned(16)));

  const int g = blockIdx.x;
  const int khalf = (g >> 2) & 1;
  const int mtile = ((g >> 3) << 2) | (g & 3);
  const int m0 = mtile * 32;

  const int tid = threadIdx.x;
  const int lane = tid & 63;
  const int wid = tid >> 6;  // 0..3 = N group: experts wid*64..+64
  const int lr = lane & 15;
  const int lg = lane >> 4;

  // W per-lane byte offset within a step image. For expert e = wid*64+n*16+lr:
  // e&6 == lr&6, so the swizzle term is n-independent and n folds into an
  // imm offset of n*1024 bytes.
  const int wOff = (wid * 64 + lr) * 64 + ((lg * 16) ^ ((lr & 6) << 3));
  const unsigned char* wH = ws + (size_t)khalf * KH * WTILE + wOff;
  const unsigned char* wL = wH + 16384;

  // A frag byte offsets (XOR-swizzled), m = 0,1 -> rows m*16+lr
  int aOff0, aOff1;
  {
    int r0 = lr, r1 = 16 + lr;
    aOff0 = r0 * 64 + ((lg * 16) ^ ((r0 & 6) << 3));
    aOff1 = r1 * 64 + ((lg * 16) ^ ((r1 & 6) << 3));
  }

  // X staging: 256 threads cover 32 rows x 8 chunks of 4 floats
  const int xr = tid >> 3;
  const int xkc = tid & 7;
  const float* xsrc = X + (size_t)(m0 + xr) * K_DIM + (size_t)khalf * KH * BK + xkc * 4;
  const int xcol = (xkc * 8) ^ ((xr & 6) << 3);

  auto write_x = [&](int b, const f32x4& xv) {
    float v[4] = {xv[0] * SX, xv[1] * SX, xv[2] * SX, xv[3] * SX};
    half4 h, l;
    cvt4_2(v, h, l);
    unsigned char* Ab = smem + b * 4096;
    *(half4*)(Ab + xr * 64 + xcol) = h;
    *(half4*)(Ab + 2048 + xr * 64 + xcol) = l;
  };

  f32x4 acc[2][4];   // xh*wh
  f32x4 accc[2][4];  // xh*wl + xl*wh
#pragma unroll
  for (int m = 0; m < 2; ++m)
#pragma unroll
    for (int n = 0; n < 4; ++n) {
      acc[m][n] = (f32x4){0.f, 0.f, 0.f, 0.f};
      accc[m][n] = (f32x4){0.f, 0.f, 0.f, 0.f};
    }

#define CLUSTER(N, WH, WL)                                                        \
  acc[0][N] = __builtin_amdgcn_mfma_f32_16x16x32_f16(xh0, WH, acc[0][N], 0, 0, 0); \
  acc[1][N] = __builtin_amdgcn_mfma_f32_16x16x32_f16(xh1, WH, acc[1][N], 0, 0, 0); \
  accc[0][N] = __builtin_amdgcn_mfma_f32_16x16x32_f16(xl0, WH, accc[0][N], 0, 0, 0); \
  accc[1][N] = __builtin_amdgcn_mfma_f32_16x16x32_f16(xl1, WH, accc[1][N], 0, 0, 0); \
  accc[0][N] = __builtin_amdgcn_mfma_f32_16x16x32_f16(xh0, WL, accc[0][N], 0, 0, 0); \
  accc[1][N] = __builtin_amdgcn_mfma_f32_16x16x32_f16(xh1, WL, accc[1][N], 0, 0, 0);

  // One step. Only A lives in LDS -> barrier waits lgkmcnt(0) only; W loads
  // are wave-private (compiler-counted vmcnt before their MFMAs).
  auto body = [&](int t, int cur) {
    f32x4 xq;
    const bool hasNext = (t + 1 < KH);
    if (hasNext)
      xq = __builtin_nontemporal_load((const f32x4*)(xsrc + (size_t)(t + 1) * BK));

    const unsigned char* wpH = wH + (size_t)t * WTILE;
    const unsigned char* wpL = wL + (size_t)t * WTILE;
    // W batch A (n=0,1)
    half8 wh0 = *(const half8*)(wpH);
    half8 wh1 = *(const half8*)(wpH + 1024);
    half8 wl0 = *(const half8*)(wpL);
    half8 wl1 = *(const half8*)(wpL + 1024);

    const unsigned char* Ab = smem + cur * 4096;
    half8 xh0 = *(const half8*)(Ab + aOff0);
    half8 xh1 = *(const half8*)(Ab + aOff1);
    half8 xl0 = *(const half8*)(Ab + 2048 + aOff0);
    half8 xl1 = *(const half8*)(Ab + 2048 + aOff1);

    __builtin_amdgcn_s_setprio(1);
    CLUSTER(0, wh0, wl0)
    CLUSTER(1, wh1, wl1)
    __builtin_amdgcn_s_setprio(0);
    __builtin_amdgcn_sched_barrier(0);  // keep batch B out of batch A liveness

    // W batch B (n=2,3)
    half8 wh2 = *(const half8*)(wpH + 2048);
    half8 wh3 = *(const half8*)(wpH + 3072);
    half8 wl2 = *(const half8*)(wpL + 2048);
    half8 wl3 = *(const half8*)(wpL + 3072);

    __builtin_amdgcn_s_setprio(1);
    CLUSTER(2, wh2, wl2)
    CLUSTER(3, wh3, wl3)
    __builtin_amdgcn_s_setprio(0);

    if (hasNext) {
      write_x(cur ^ 1, xq);  // compiler waits xq's load (oldest) automatically
      asm volatile("s_waitcnt lgkmcnt(0)" ::: "memory");
      __builtin_amdgcn_s_barrier();
    }
  };

  // prologue: A(0) into buf0
  {
    f32x4 x0 = __builtin_nontemporal_load((const f32x4*)xsrc);
    write_x(0, x0);
    __syncthreads();
  }

#pragma clang loop unroll(disable)
  for (int t = 0; t < KH; t += 2) {
    body(t, 0);
    body(t + 1, 1);
  }
#undef CLUSTER

  // ---- epilogue: raw prescaled partial logits -> part[khalf] (NT stores)
  float* dst = part + (size_t)khalf * P_ELEMS;
#pragma unroll
  for (int m = 0; m < 2; ++m)
#pragma unroll
    for (int n = 0; n < 4; ++n)
#pragma unroll
      for (int r = 0; r < 4; ++r) {
        int row = m * 16 + lg * 4 + r;
        int col = wid * 64 + n * 16 + lr;
        __builtin_nontemporal_store(acc[m][n][r] + accc[m][n][r],
                                    &dst[(size_t)(m0 + row) * N_EXP + col]);
      }
}

// ---------------------------------------------------------------------------
// Reducer: add the two K-half partials, descale, sigmoid, fused top-8.
// Grid 512 x 256 threads; block handles 32 rows.
// ---------------------------------------------------------------------------
__global__ __launch_bounds__(256) void reduce_topk_kernel(
    const float* __restrict__ part,
    const float* __restrict__ bias,
    float* __restrict__ out) {
  __shared__ float sc[32 * 260];

  const int tid = threadIdx.x;
  const int lane = tid & 63;
  const int wid = tid >> 6;
  const int r0 = blockIdx.x * 32;

  const float* p0 = part;
  const float* p1 = part + P_ELEMS;

  {
    int row = tid >> 3, seg = tid & 7;
    size_t base = (size_t)(r0 + row) * N_EXP + seg * 32;
#pragma unroll
    for (int j = 0; j < 8; ++j) {
      f32x4 a = __builtin_nontemporal_load((const f32x4*)(p0 + base + j * 4));
      f32x4 b = __builtin_nontemporal_load((const f32x4*)(p1 + base + j * 4));
#pragma unroll
      for (int e = 0; e < 4; ++e) {
        float v = (a[e] + b[e]) * DESCALE;
        sc[row * 260 + seg * 32 + j * 4 + e] = 1.0f / (1.0f + expf(-v));
      }
    }
  }
  __syncthreads();

  const float bb0 = bias[lane];
  const float bb1 = bias[lane + 64];
  const float bb2 = bias[lane + 128];
  const float bb3 = bias[lane + 192];
  const size_t TOT = (size_t)M_TOK * TOPK;

  for (int i = 0; i < 8; ++i) {
    int row = wid * 8 + i;
    float s0 = sc[row * 260 + lane];
    float s1 = sc[row * 260 + lane + 64];
    float s2 = sc[row * 260 + lane + 128];
    float s3 = sc[row * 260 + lane + 192];
    unsigned long long c0 = pack_ci(s0 + bb0, lane);
    unsigned long long c1 = pack_ci(s1 + bb1, lane + 64);
    unsigned long long c2 = pack_ci(s2 + bb2, lane + 128);
    unsigned long long c3 = pack_ci(s3 + bb3, lane + 192);
    float ssum = 0.f, my_s = 0.f;
    int my_idx = 0;
#pragma unroll
    for (int p = 0; p < TOPK; ++p) {
      unsigned long long b01 = c0 > c1 ? c0 : c1;
      unsigned long long b23 = c2 > c3 ? c2 : c3;
      unsigned long long best = b01 > b23 ? b01 : b23;
#pragma unroll
      for (int off = 1; off < 64; off <<= 1) {
        unsigned long long o = shflx64(best, off);
        if (o > best) best = o;
      }
      int idxw = 255 - (int)(best & 0xffull);
      int lw = idxw & 63;
      int jw = idxw >> 6;
      float sel = jw == 0 ? s0 : jw == 1 ? s1 : jw == 2 ? s2 : s3;
      float sw = __shfl(sel, lw);
      ssum += sw;
      if (lane == p) { my_idx = idxw; my_s = sw; }
      if (lane == lw) {
        if (jw == 0) c0 = 0ull;
        else if (jw == 1) c1 = 0ull;
        else if (jw == 2) c2 = 0ull;
        else c3 = 0ull;
      }
    }
    if (lane < TOPK) {
      size_t rg = (size_t)(r0 + row);
      out[rg * TOPK + lane] = (float)my_idx;
      out[TOT + rg * TOPK + lane] = my_s * (2.5f / (ssum + 1e-20f));
    }
  }
}

// ---------------------------------------------------------------------------
// Fallback (ws too small): monolithic kernel, W from Wg with on-the-fly split.
// ---------------------------------------------------------------------------
__global__ __launch_bounds__(512, 2) void gate_mono_kernel(
    const float* __restrict__ X,
    const float* __restrict__ Wg,
    const float* __restrict__ bias,
    float* __restrict__ out) {
  __shared__ unsigned char smem[81920] __attribute__((aligned(16)));

  const int tid = threadIdx.x;
  const int lane = tid & 63;
  const int wid = tid >> 6;
  const int wm = wid >> 2;
  const int wn = wid & 3;
  const int lr = lane & 15;
  const int lg = lane >> 4;
  const int m0 = blockIdx.x * 64;

  int aOff[2], bOff[4];
#pragma unroll
  for (int m = 0; m < 2; ++m) {
    int r = wm * 32 + m * 16 + lr;
    aOff[m] = r * 64 + ((lg * 16) ^ ((r & 6) << 3));
  }
#pragma unroll
  for (int n = 0; n < 4; ++n) {
    int e = wn * 64 + n * 16 + lr;
    bOff[n] = e * 64 + ((lg * 16) ^ ((e & 6) << 3));
  }

  const int xr = tid >> 3;
  const int xkc = tid & 7;
  const float* xsrc = X + (size_t)(m0 + xr) * K_DIM + xkc * 4;
  const int xcol = (xkc * 8) ^ ((xr & 6) << 3);

  auto load_x = [&](int t, f32x4& dst) {
    dst = *(const f32x4*)(xsrc + (size_t)t * BK);
  };
  auto write_x = [&](int b, const f32x4& xv) {
    float v[4] = {xv[0] * SX, xv[1] * SX, xv[2] * SX, xv[3] * SX};
    half4 h, l;
    cvt4_2(v, h, l);
    unsigned char* Ab = smem + b * 8192;
    *(half4*)(Ab + xr * 64 + xcol) = h;
    *(half4*)(Ab + 4096 + xr * 64 + xcol) = l;
  };
  auto stage_w = [&](int t, int b) {
    unsigned char* Bb = smem + 16384 + b * 32768;
    int row = tid >> 1;
    int g0 = (tid & 1) * 2;
    const float* src = Wg + (size_t)row * K_DIM + (size_t)t * BK + g0 * 8;
#pragma unroll
    for (int g = 0; g < 2; ++g) {
      float v[8];
      float4 a = ((const float4*)src)[g * 2];
      float4 bq = ((const float4*)src)[g * 2 + 1];
      v[0] = a.x * SW; v[1] = a.y * SW; v[2] = a.z * SW; v[3] = a.w * SW;
      v[4] = bq.x * SW; v[5] = bq.y * SW; v[6] = bq.z * SW; v[7] = bq.w * SW;
      half8 h, l;
      cvt8_2(v, h, l);
      int col = ((g0 + g) * 16) ^ ((row & 6) << 3);
      *(half8*)(Bb + row * 64 + col) = h;
      *(half8*)(Bb + 16384 + row * 64 + col) = l;
    }
  };

  f32x4 acc[2][4], accc[2][4];
#pragma unroll
  for (int m = 0; m < 2; ++m)
#pragma unroll
    for (int n = 0; n < 4; ++n) {
      acc[m][n] = (f32x4){0.f, 0.f, 0.f, 0.f};
      accc[m][n] = (f32x4){0.f, 0.f, 0.f, 0.f};
    }

  f32x4 xqA, xqB;
  stage_w(0, 0);
  load_x(0, xqA);
  write_x(0, xqA);
  load_x(1, xqB);
  __syncthreads();

#pragma clang loop unroll(disable)
  for (int t = 0; t < KSTEPS; ++t) {
    const int cur = t & 1, nxt = cur ^ 1;
    f32x4& xload = (t & 1) ? xqB : xqA;
    const f32x4& xcons = (t & 1) ? xqA : xqB;
    if (t + 1 < KSTEPS) stage_w(t + 1, nxt);
    if (t + 2 < KSTEPS) load_x(t + 2, xload);

    const unsigned char* Ab = smem + cur * 8192;
    const unsigned char* Bb = smem + 16384 + cur * 32768;
    half8 xh[2], xl[2], wh[4], wl[4];
#pragma unroll
    for (int m = 0; m < 2; ++m) {
      xh[m] = *(const half8*)(Ab + aOff[m]);
      xl[m] = *(const half8*)(Ab + 4096 + aOff[m]);
    }
#pragma unroll
    for (int n = 0; n < 4; ++n) {
      wh[n] = *(const half8*)(Bb + bOff[n]);
      wl[n] = *(const half8*)(Bb + 16384 + bOff[n]);
    }
#pragma unroll
    for (int m = 0; m < 2; ++m)
#pragma unroll
      for (int n = 0; n < 4; ++n) {
        acc[m][n] = __builtin_amdgcn_mfma_f32_16x16x32_f16(xh[m], wh[n], acc[m][n], 0, 0, 0);
        f32x4 c = accc[m][n];
        c = __builtin_amdgcn_mfma_f32_16x16x32_f16(xh[m], wl[n], c, 0, 0, 0);
        c = __builtin_amdgcn_mfma_f32_16x16x32_f16(xl[m], wh[n], c, 0, 0, 0);
        accc[m][n] = c;
      }
    if (t + 1 < KSTEPS) {
      write_x(nxt, xcons);
      __syncthreads();
    }
  }
  __syncthreads();

  float* sc = (float*)smem;
#pragma unroll
  for (int m = 0; m < 2; ++m)
#pragma unroll
    for (int n = 0; n < 4; ++n)
#pragma unroll
      for (int r = 0; r < 4; ++r) {
        int row = wm * 32 + m * 16 + lg * 4 + r;
        int col = wn * 64 + n * 16 + lr;
        float v = (acc[m][n][r] + accc[m][n][r]) * DESCALE;
        sc[row * 260 + col] = 1.0f / (1.0f + expf(-v));
      }
  __syncthreads();

  const float bb0 = bias[lane];
  const float bb1 = bias[lane + 64];
  const float bb2 = bias[lane + 128];
  const float bb3 = bias[lane + 192];
  const size_t TOT = (size_t)M_TOK * TOPK;

  for (int i = 0; i < 8; ++i) {
    int row = wid * 8 + i;
    float s0 = sc[row * 260 + lane];
    float s1 = sc[row * 260 + lane + 64];
    float s2 = sc[row * 260 + lane + 128];
    float s3 = sc[row * 260 + lane + 192];
    unsigned long long c0 = pack_ci(s0 + bb0, lane);
    unsigned long long c1 = pack_ci(s1 + bb1, lane + 64);
    unsigned long long c2 = pack_ci(s2 + bb2, lane + 128);
    unsigned long long c3 = pack_ci(s3 + bb3, lane + 192);
    float ssum = 0.f, my_s = 0.f;
    int my_idx = 0;
#pragma unroll
    for (int p = 0; p < TOPK; ++p) {
      unsigned long long b01 = c0 > c1 ? c0 : c1;
      unsigned long long b23 = c2 > c3 ? c2 : c3;
      unsigned long long best = b01 > b23 ? b01 : b23;
#pragma unroll
      for (int off = 1; off < 64; off <<= 1) {
        unsigned long long o = shflx64(best, off);
        if (o > best) best = o;
      }
      int idxw = 255 - (int)(best & 0xffull);
      int lw = idxw & 63;
      int jw = idxw >> 6;
      float sel = jw == 0 ? s0 : jw == 1 ? s1 : jw == 2 ? s2 : s3;
      float sw = __shfl(sel, lw);
      ssum += sw;
      if (lane == p) { my_idx = idxw; my_s = sw; }
      if (lane == lw) {
        if (jw == 0) c0 = 0ull;
        else if (jw == 1) c1 = 0ull;
        else if (jw == 2) c2 = 0ull;
        else c3 = 0ull;
      }
    }
    if (lane < TOPK) {
      size_t rg = (size_t)(m0 + row);
      out[rg * TOPK + lane] = (float)my_idx;
      out[TOT + rg * TOPK + lane] = my_s * (2.5f / (ssum + 1e-20f));
    }
  }
}

extern "C" void kernel_launch(void* const* d_in, const int* in_sizes, int n_in,
                              void* d_out, int out_size, void* d_ws, size_t ws_size,
                              hipStream_t stream) {
  const float* X = (const float*)d_in[0];
  const float* W = (const float*)d_in[1];
  const float* bias = (const float*)d_in[2];
  float* out = (float*)d_out;

  const size_t need = IMG_BYTES + 2 * P_ELEMS * sizeof(float);  // ~40.9 MB
  if (d_ws != nullptr && ws_size >= need) {
    unsigned char* ws = (unsigned char*)d_ws;
    float* part = (float*)(ws + IMG_BYTES);
    prep_w_kernel<<<KSTEPS, 256, 0, stream>>>(W, ws);
    gate_split_kernel<<<2 * (M_TOK / 32), 256, 0, stream>>>(X, ws, part);
    reduce_topk_kernel<<<M_TOK / 32, 256, 0, stream>>>(part, bias, out);
  } else {
    gate_mono_kernel<<<M_TOK / 64, 512, 0, stream>>>(X, W, bias, out);
  }
}

// Round 11
// 306.182 us; speedup vs baseline: 1.0225x; 1.0225x over previous
//
#include <hip/hip_runtime.h>
#include <hip/hip_bf16.h>
#include <math.h>

#define M_TOK 16384
#define N_EXP 256
#define K_DIM 7168
#define BK 32
#define KSTEPS (K_DIM / BK)  /* 224 */
#define KH (KSTEPS / 2)      /* 112 steps per K-half */
#define WTILE 32768          /* bytes per k-step W image: 16KB hi + 16KB lo (fp16) */
#define IMG_BYTES ((size_t)KSTEPS * WTILE)  /* 7.34 MB */
#define P_ELEMS ((size_t)M_TOK * N_EXP)
#define TOPK 8
#define SX 4096.0f
#define SW 16384.0f
#define DESCALE 1.4901161193847656e-08f /* 2^-26 */

typedef __attribute__((ext_vector_type(8))) _Float16 half8;
typedef __attribute__((ext_vector_type(4))) _Float16 half4;
typedef __attribute__((ext_vector_type(4))) float f32x4;

__device__ __forceinline__ void cvt8_2(const float* v, half8& h, half8& l) {
#pragma unroll
  for (int i = 0; i < 8; ++i) {
    _Float16 a = (_Float16)v[i];
    float r = v[i] - (float)a;
    h[i] = a;
    l[i] = (_Float16)r;
  }
}
__device__ __forceinline__ void cvt4_2(const float* v, half4& h, half4& l) {
#pragma unroll
  for (int i = 0; i < 4; ++i) {
    _Float16 a = (_Float16)v[i];
    float r = v[i] - (float)a;
    h[i] = a;
    l[i] = (_Float16)r;
  }
}

__device__ __forceinline__ unsigned long long pack_ci(float key, int idx) {
  unsigned int u = __builtin_bit_cast(unsigned int, key);
  u = (u & 0x80000000u) ? ~u : (u | 0x80000000u);
  return ((unsigned long long)u << 32) | (unsigned)(255 - idx);
}
__device__ __forceinline__ unsigned long long shflx64(unsigned long long v, int off) {
  int lo = __shfl_xor((int)(unsigned)(v & 0xffffffffull), off);
  int hi = __shfl_xor((int)(unsigned)(v >> 32), off);
  return ((unsigned long long)(unsigned)hi << 32) | (unsigned)lo;
}

// gate_weight fp32 [256][7168] -> per-kstep swizzled fp16 images in ws.
// Image t (32KB): hi plane [256 rows][64B] at +0, lo plane at +16384.
// byte col of 16B granule kc: (kc*16) ^ ((e&6)<<3).
__global__ void prep_w_kernel(const float* __restrict__ W, unsigned char* __restrict__ ws) {
  int t = blockIdx.x;
  int e = threadIdx.x;
  const float* src = W + (size_t)e * K_DIM + t * BK;
  unsigned char* dst = ws + (size_t)t * WTILE;
#pragma unroll
  for (int kc = 0; kc < 4; ++kc) {
    float v[8];
    float4 a = ((const float4*)src)[kc * 2];
    float4 b = ((const float4*)src)[kc * 2 + 1];
    v[0] = a.x * SW; v[1] = a.y * SW; v[2] = a.z * SW; v[3] = a.w * SW;
    v[4] = b.x * SW; v[5] = b.y * SW; v[6] = b.z * SW; v[7] = b.w * SW;
    half8 h, l;
    cvt8_2(v, h, l);
    int col = (kc * 16) ^ ((e & 6) << 3);
    *(half8*)(dst + e * 64 + col) = h;
    *(half8*)(dst + 16384 + e * 64 + col) = l;
  }
}

// ---------------------------------------------------------------------------
// K-split GEMM: BM=128, full N=256 per block, A-only LDS, W global->reg.
// Grid 256 = 128 M-tiles x 2 K-halves; khalf = g&1 -> even XCDs serve half 0,
// odd XCDs half 1 (3.67MB half-image per XCD L2). 512 thr = 8 waves (2m x 4n),
// wave tile 64x64. Barrier guards ONLY the A-tile dbuf (lgkmcnt; no vmcnt).
// ---------------------------------------------------------------------------
__global__ __launch_bounds__(512, 2) void gate_split_kernel(
    const float* __restrict__ X,
    const unsigned char* __restrict__ ws,
    float* __restrict__ part) {
  // LDS: A dbuf [2][16KB]; buf b at b*16384: hi plane [128 rows][64B], lo +8192.
  __shared__ unsigned char smem[32768] __attribute__((aligned(16)));

  const int g = blockIdx.x;
  const int khalf = g & 1;
  const int m0 = (g >> 1) * 128;

  const int tid = threadIdx.x;
  const int lane = tid & 63;
  const int wid = tid >> 6;  // 0..7
  const int wm = wid >> 2;   // 0..1: rows wm*64..+64
  const int wn = wid & 3;    // 0..3: experts wn*64..+64
  const int lr = lane & 15;
  const int lg = lane >> 4;

  // W per-lane byte offset in a step image; expert e = wn*64 + n*16 + lr has
  // e&6 == lr&6, so n folds into +n*1024.
  const unsigned char* img0 = ws + (size_t)khalf * KH * WTILE;
  const int wOff = (wn * 64 + lr) * 64 + ((lg * 16) ^ ((lr & 6) << 3));

  // A frag byte offsets (XOR-swizzled), m = 0..3 -> rows wm*64 + m*16 + lr
  int aOff[4];
#pragma unroll
  for (int m = 0; m < 4; ++m) {
    int r = wm * 64 + m * 16 + lr;
    aOff[m] = r * 64 + ((lg * 16) ^ ((r & 6) << 3));
  }

  // X staging: 512 threads cover 128 rows x 4 chunks of 8 floats
  const int xr = tid >> 2;
  const int xkc = tid & 3;
  const float* xsrc = X + (size_t)(m0 + xr) * K_DIM + (size_t)khalf * KH * BK + xkc * 8;
  const int xcol = (xkc * 16) ^ ((xr & 6) << 3);

  auto write_x = [&](int b, const f32x4& x0, const f32x4& x1) {
    float v[8] = {x0[0] * SX, x0[1] * SX, x0[2] * SX, x0[3] * SX,
                  x1[0] * SX, x1[1] * SX, x1[2] * SX, x1[3] * SX};
    half8 h, l;
    cvt8_2(v, h, l);
    unsigned char* Ab = smem + b * 16384;
    *(half8*)(Ab + xr * 64 + xcol) = h;
    *(half8*)(Ab + 8192 + xr * 64 + xcol) = l;
  };

  f32x4 acc[4][4];   // xh*wh
  f32x4 accc[4][4];  // xl*wh + xh*wl
#pragma unroll
  for (int m = 0; m < 4; ++m)
#pragma unroll
    for (int n = 0; n < 4; ++n) {
      acc[m][n] = (f32x4){0.f, 0.f, 0.f, 0.f};
      accc[m][n] = (f32x4){0.f, 0.f, 0.f, 0.f};
    }

  // prologue: A(0) into buf0
  {
    f32x4 x0 = __builtin_nontemporal_load((const f32x4*)xsrc);
    f32x4 x1 = __builtin_nontemporal_load((const f32x4*)(xsrc + 4));
    write_x(0, x0, x1);
    __syncthreads();
  }

#pragma clang loop unroll(disable)
  for (int t = 0; t < KH; ++t) {
    const int cur = t & 1;
    const bool hasNext = (t + 1 < KH);

    // X(t+1) -> regs (in flight across this step's MFMAs; no barrier coupling)
    f32x4 xq0, xq1;
    if (hasNext) {
      xq0 = __builtin_nontemporal_load((const f32x4*)(xsrc + (size_t)(t + 1) * BK));
      xq1 = __builtin_nontemporal_load((const f32x4*)(xsrc + (size_t)(t + 1) * BK + 4));
    }

    // W(t) fragments: L2 -> regs, 8 x 16B coalesced (1KB contiguous per frag)
    const unsigned char* wp = img0 + (size_t)t * WTILE + wOff;
    half8 wh[4], wl[4];
#pragma unroll
    for (int n = 0; n < 4; ++n) wh[n] = *(const half8*)(wp + n * 1024);
#pragma unroll
    for (int n = 0; n < 4; ++n) wl[n] = *(const half8*)(wp + 16384 + n * 1024);

    const unsigned char* Ab = smem + cur * 16384;
#pragma unroll
    for (int m = 0; m < 4; ++m) {
      half8 xh = *(const half8*)(Ab + aOff[m]);
      half8 xl = *(const half8*)(Ab + 8192 + aOff[m]);
#pragma unroll
      for (int n = 0; n < 4; ++n) {
        acc[m][n] = __builtin_amdgcn_mfma_f32_16x16x32_f16(xh, wh[n], acc[m][n], 0, 0, 0);
        f32x4 c = accc[m][n];
        c = __builtin_amdgcn_mfma_f32_16x16x32_f16(xl, wh[n], c, 0, 0, 0);
        c = __builtin_amdgcn_mfma_f32_16x16x32_f16(xh, wl[n], c, 0, 0, 0);
        accc[m][n] = c;
      }
    }

    if (hasNext) {
      write_x(cur ^ 1, xq0, xq1);  // compiler waits xq's loads before ds_write
      asm volatile("s_waitcnt lgkmcnt(0)" ::: "memory");
      __builtin_amdgcn_s_barrier();
    }
  }

  // ---- epilogue: raw prescaled partial logits -> part[khalf] (NT stores)
  float* dst = part + (size_t)khalf * P_ELEMS + (size_t)m0 * N_EXP;
#pragma unroll
  for (int m = 0; m < 4; ++m)
#pragma unroll
    for (int n = 0; n < 4; ++n)
#pragma unroll
      for (int r = 0; r < 4; ++r) {
        int row = wm * 64 + m * 16 + lg * 4 + r;
        int col = wn * 64 + n * 16 + lr;
        __builtin_nontemporal_store(acc[m][n][r] + accc[m][n][r],
                                    &dst[(size_t)row * N_EXP + col]);
      }
}

// ---------------------------------------------------------------------------
// Reducer: add the two K-half partials, descale, sigmoid, fused top-8.
// Grid 512 x 256 threads; block handles 32 rows.
// ---------------------------------------------------------------------------
__global__ __launch_bounds__(256) void reduce_topk_kernel(
    const float* __restrict__ part,
    const float* __restrict__ bias,
    float* __restrict__ out) {
  __shared__ float sc[32 * 260];

  const int tid = threadIdx.x;
  const int lane = tid & 63;
  const int wid = tid >> 6;
  const int r0 = blockIdx.x * 32;

  const float* p0 = part;
  const float* p1 = part + P_ELEMS;

  {
    int row = tid >> 3, seg = tid & 7;
    size_t base = (size_t)(r0 + row) * N_EXP + seg * 32;
#pragma unroll
    for (int j = 0; j < 8; ++j) {
      f32x4 a = __builtin_nontemporal_load((const f32x4*)(p0 + base + j * 4));
      f32x4 b = __builtin_nontemporal_load((const f32x4*)(p1 + base + j * 4));
#pragma unroll
      for (int e = 0; e < 4; ++e) {
        float v = (a[e] + b[e]) * DESCALE;
        sc[row * 260 + seg * 32 + j * 4 + e] = 1.0f / (1.0f + expf(-v));
      }
    }
  }
  __syncthreads();

  const float bb0 = bias[lane];
  const float bb1 = bias[lane + 64];
  const float bb2 = bias[lane + 128];
  const float bb3 = bias[lane + 192];
  const size_t TOT = (size_t)M_TOK * TOPK;

  for (int i = 0; i < 8; ++i) {
    int row = wid * 8 + i;
    float s0 = sc[row * 260 + lane];
    float s1 = sc[row * 260 + lane + 64];
    float s2 = sc[row * 260 + lane + 128];
    float s3 = sc[row * 260 + lane + 192];
    unsigned long long c0 = pack_ci(s0 + bb0, lane);
    unsigned long long c1 = pack_ci(s1 + bb1, lane + 64);
    unsigned long long c2 = pack_ci(s2 + bb2, lane + 128);
    unsigned long long c3 = pack_ci(s3 + bb3, lane + 192);
    float ssum = 0.f, my_s = 0.f;
    int my_idx = 0;
#pragma unroll
    for (int p = 0; p < TOPK; ++p) {
      unsigned long long b01 = c0 > c1 ? c0 : c1;
      unsigned long long b23 = c2 > c3 ? c2 : c3;
      unsigned long long best = b01 > b23 ? b01 : b23;
#pragma unroll
      for (int off = 1; off < 64; off <<= 1) {
        unsigned long long o = shflx64(best, off);
        if (o > best) best = o;
      }
      int idxw = 255 - (int)(best & 0xffull);
      int lw = idxw & 63;
      int jw = idxw >> 6;
      float sel = jw == 0 ? s0 : jw == 1 ? s1 : jw == 2 ? s2 : s3;
      float sw = __shfl(sel, lw);
      ssum += sw;
      if (lane == p) { my_idx = idxw; my_s = sw; }
      if (lane == lw) {
        if (jw == 0) c0 = 0ull;
        else if (jw == 1) c1 = 0ull;
        else if (jw == 2) c2 = 0ull;
        else c3 = 0ull;
      }
    }
    if (lane < TOPK) {
      size_t rg = (size_t)(r0 + row);
      out[rg * TOPK + lane] = (float)my_idx;
      out[TOT + rg * TOPK + lane] = my_s * (2.5f / (ssum + 1e-20f));
    }
  }
}

// ---------------------------------------------------------------------------
// Fallback (ws too small): monolithic kernel, W from Wg with on-the-fly split.
// ---------------------------------------------------------------------------
__global__ __launch_bounds__(512, 2) void gate_mono_kernel(
    const float* __restrict__ X,
    const float* __restrict__ Wg,
    const float* __restrict__ bias,
    float* __restrict__ out) {
  __shared__ unsigned char smem[81920] __attribute__((aligned(16)));

  const int tid = threadIdx.x;
  const int lane = tid & 63;
  const int wid = tid >> 6;
  const int wm = wid >> 2;
  const int wn = wid & 3;
  const int lr = lane & 15;
  const int lg = lane >> 4;
  const int m0 = blockIdx.x * 64;

  int aOff[2], bOff[4];
#pragma unroll
  for (int m = 0; m < 2; ++m) {
    int r = wm * 32 + m * 16 + lr;
    aOff[m] = r * 64 + ((lg * 16) ^ ((r & 6) << 3));
  }
#pragma unroll
  for (int n = 0; n < 4; ++n) {
    int e = wn * 64 + n * 16 + lr;
    bOff[n] = e * 64 + ((lg * 16) ^ ((e & 6) << 3));
  }

  const int xr = tid >> 3;
  const int xkc = tid & 7;
  const float* xsrc = X + (size_t)(m0 + xr) * K_DIM + xkc * 4;
  const int xcol = (xkc * 8) ^ ((xr & 6) << 3);

  auto load_x = [&](int t, f32x4& dst) {
    dst = *(const f32x4*)(xsrc + (size_t)t * BK);
  };
  auto write_x = [&](int b, const f32x4& xv) {
    float v[4] = {xv[0] * SX, xv[1] * SX, xv[2] * SX, xv[3] * SX};
    half4 h, l;
    cvt4_2(v, h, l);
    unsigned char* Ab = smem + b * 8192;
    *(half4*)(Ab + xr * 64 + xcol) = h;
    *(half4*)(Ab + 4096 + xr * 64 + xcol) = l;
  };
  auto stage_w = [&](int t, int b) {
    unsigned char* Bb = smem + 16384 + b * 32768;
    int row = tid >> 1;
    int g0 = (tid & 1) * 2;
    const float* src = Wg + (size_t)row * K_DIM + (size_t)t * BK + g0 * 8;
#pragma unroll
    for (int g = 0; g < 2; ++g) {
      float v[8];
      float4 a = ((const float4*)src)[g * 2];
      float4 bq = ((const float4*)src)[g * 2 + 1];
      v[0] = a.x * SW; v[1] = a.y * SW; v[2] = a.z * SW; v[3] = a.w * SW;
      v[4] = bq.x * SW; v[5] = bq.y * SW; v[6] = bq.z * SW; v[7] = bq.w * SW;
      half8 h, l;
      cvt8_2(v, h, l);
      int col = ((g0 + g) * 16) ^ ((row & 6) << 3);
      *(half8*)(Bb + row * 64 + col) = h;
      *(half8*)(Bb + 16384 + row * 64 + col) = l;
    }
  };

  f32x4 acc[2][4], accc[2][4];
#pragma unroll
  for (int m = 0; m < 2; ++m)
#pragma unroll
    for (int n = 0; n < 4; ++n) {
      acc[m][n] = (f32x4){0.f, 0.f, 0.f, 0.f};
      accc[m][n] = (f32x4){0.f, 0.f, 0.f, 0.f};
    }

  f32x4 xqA, xqB;
  stage_w(0, 0);
  load_x(0, xqA);
  write_x(0, xqA);
  load_x(1, xqB);
  __syncthreads();

#pragma clang loop unroll(disable)
  for (int t = 0; t < KSTEPS; ++t) {
    const int cur = t & 1, nxt = cur ^ 1;
    f32x4& xload = (t & 1) ? xqB : xqA;
    const f32x4& xcons = (t & 1) ? xqA : xqB;
    if (t + 1 < KSTEPS) stage_w(t + 1, nxt);
    if (t + 2 < KSTEPS) load_x(t + 2, xload);

    const unsigned char* Ab = smem + cur * 8192;
    const unsigned char* Bb = smem + 16384 + cur * 32768;
    half8 xh[2], xl[2], wh[4], wl[4];
#pragma unroll
    for (int m = 0; m < 2; ++m) {
      xh[m] = *(const half8*)(Ab + aOff[m]);
      xl[m] = *(const half8*)(Ab + 4096 + aOff[m]);
    }
#pragma unroll
    for (int n = 0; n < 4; ++n) {
      wh[n] = *(const half8*)(Bb + bOff[n]);
      wl[n] = *(const half8*)(Bb + 16384 + bOff[n]);
    }
#pragma unroll
    for (int m = 0; m < 2; ++m)
#pragma unroll
      for (int n = 0; n < 4; ++n) {
        acc[m][n] = __builtin_amdgcn_mfma_f32_16x16x32_f16(xh[m], wh[n], acc[m][n], 0, 0, 0);
        f32x4 c = accc[m][n];
        c = __builtin_amdgcn_mfma_f32_16x16x32_f16(xh[m], wl[n], c, 0, 0, 0);
        c = __builtin_amdgcn_mfma_f32_16x16x32_f16(xl[m], wh[n], c, 0, 0, 0);
        accc[m][n] = c;
      }
    if (t + 1 < KSTEPS) {
      write_x(nxt, xcons);
      __syncthreads();
    }
  }
  __syncthreads();

  float* sc = (float*)smem;
#pragma unroll
  for (int m = 0; m < 2; ++m)
#pragma unroll
    for (int n = 0; n < 4; ++n)
#pragma unroll
      for (int r = 0; r < 4; ++r) {
        int row = wm * 32 + m * 16 + lg * 4 + r;
        int col = wn * 64 + n * 16 + lr;
        float v = (acc[m][n][r] + accc[m][n][r]) * DESCALE;
        sc[row * 260 + col] = 1.0f / (1.0f + expf(-v));
      }
  __syncthreads();

  const float bb0 = bias[lane];
  const float bb1 = bias[lane + 64];
  const float bb2 = bias[lane + 128];
  const float bb3 = bias[lane + 192];
  const size_t TOT = (size_t)M_TOK * TOPK;

  for (int i = 0; i < 8; ++i) {
    int row = wid * 8 + i;
    float s0 = sc[row * 260 + lane];
    float s1 = sc[row * 260 + lane + 64];
    float s2 = sc[row * 260 + lane + 128];
    float s3 = sc[row * 260 + lane + 192];
    unsigned long long c0 = pack_ci(s0 + bb0, lane);
    unsigned long long c1 = pack_ci(s1 + bb1, lane + 64);
    unsigned long long c2 = pack_ci(s2 + bb2, lane + 128);
    unsigned long long c3 = pack_ci(s3 + bb3, lane + 192);
    float ssum = 0.f, my_s = 0.f;
    int my_idx = 0;
#pragma unroll
    for (int p = 0; p < TOPK; ++p) {
      unsigned long long b01 = c0 > c1 ? c0 : c1;
      unsigned long long b23 = c2 > c3 ? c2 : c3;
      unsigned long long best = b01 > b23 ? b01 : b23;
#pragma unroll
      for (int off = 1; off < 64; off <<= 1) {
        unsigned long long o = shflx64(best, off);
        if (o > best) best = o;
      }
      int idxw = 255 - (int)(best & 0xffull);
      int lw = idxw & 63;
      int jw = idxw >> 6;
      float sel = jw == 0 ? s0 : jw == 1 ? s1 : jw == 2 ? s2 : s3;
      float sw = __shfl(sel, lw);
      ssum += sw;
      if (lane == p) { my_idx = idxw; my_s = sw; }
      if (lane == lw) {
        if (jw == 0) c0 = 0ull;
        else if (jw == 1) c1 = 0ull;
        else if (jw == 2) c2 = 0ull;
        else c3 = 0ull;
      }
    }
    if (lane < TOPK) {
      size_t rg = (size_t)(m0 + row);
      out[rg * TOPK + lane] = (float)my_idx;
      out[TOT + rg * TOPK + lane] = my_s * (2.5f / (ssum + 1e-20f));
    }
  }
}

extern "C" void kernel_launch(void* const* d_in, const int* in_sizes, int n_in,
                              void* d_out, int out_size, void* d_ws, size_t ws_size,
                              hipStream_t stream) {
  const float* X = (const float*)d_in[0];
  const float* W = (const float*)d_in[1];
  const float* bias = (const float*)d_in[2];
  float* out = (float*)d_out;

  const size_t need = IMG_BYTES + 2 * P_ELEMS * sizeof(float);  // ~40.9 MB
  if (d_ws != nullptr && ws_size >= need) {
    unsigned char* ws = (unsigned char*)d_ws;
    float* part = (float*)(ws + IMG_BYTES);
    prep_w_kernel<<<KSTEPS, 256, 0, stream>>>(W, ws);
    gate_split_kernel<<<2 * (M_TOK / 128), 512, 0, stream>>>(X, ws, part);
    reduce_topk_kernel<<<M_TOK / 32, 256, 0, stream>>>(part, bias, out);
  } else {
    gate_mono_kernel<<<M_TOK / 64, 512, 0, stream>>>(X, W, bias, out);
  }
}

// Round 12
// 262.778 us; speedup vs baseline: 1.1913x; 1.1652x over previous
//
#include <hip/hip_runtime.h>
#include <hip/hip_bf16.h>
#include <math.h>

#define M_TOK 16384
#define N_EXP 256
#define K_DIM 7168
#define BK 32
#define KSTEPS (K_DIM / BK)  /* 224 */
#define KH (KSTEPS / 2)      /* 112 steps per K-half */
#define WTILE 32768          /* bytes per k-step W image: 16KB hi + 16KB lo (fp16) */
#define IMG_BYTES ((size_t)KSTEPS * WTILE)  /* 7.34 MB */
#define P_ELEMS ((size_t)M_TOK * N_EXP)
#define TOPK 8
#define SX 4096.0f
#define SW 16384.0f
#define DESCALE 1.4901161193847656e-08f /* 2^-26 */

typedef __attribute__((ext_vector_type(8))) _Float16 half8;
typedef __attribute__((ext_vector_type(4))) _Float16 half4;
typedef __attribute__((ext_vector_type(4))) float f32x4;

__device__ __forceinline__ void cvt8_2(const float* v, half8& h, half8& l) {
#pragma unroll
  for (int i = 0; i < 8; ++i) {
    _Float16 a = (_Float16)v[i];
    float r = v[i] - (float)a;
    h[i] = a;
    l[i] = (_Float16)r;
  }
}
__device__ __forceinline__ void cvt4_2(const float* v, half4& h, half4& l) {
#pragma unroll
  for (int i = 0; i < 4; ++i) {
    _Float16 a = (_Float16)v[i];
    float r = v[i] - (float)a;
    h[i] = a;
    l[i] = (_Float16)r;
  }
}

__device__ __forceinline__ unsigned long long pack_ci(float key, int idx) {
  unsigned int u = __builtin_bit_cast(unsigned int, key);
  u = (u & 0x80000000u) ? ~u : (u | 0x80000000u);
  return ((unsigned long long)u << 32) | (unsigned)(255 - idx);
}
__device__ __forceinline__ unsigned long long shflx64(unsigned long long v, int off) {
  int lo = __shfl_xor((int)(unsigned)(v & 0xffffffffull), off);
  int hi = __shfl_xor((int)(unsigned)(v >> 32), off);
  return ((unsigned long long)(unsigned)hi << 32) | (unsigned)lo;
}

// gate_weight fp32 [256][7168] -> per-kstep swizzled fp16 images in ws.
// Image t (32KB): hi plane [256 rows][64B] at +0, lo plane at +16384.
// byte col of 16B granule kc: (kc*16) ^ ((e&6)<<3).
__global__ void prep_w_kernel(const float* __restrict__ W, unsigned char* __restrict__ ws) {
  int t = blockIdx.x;
  int e = threadIdx.x;
  const float* src = W + (size_t)e * K_DIM + t * BK;
  unsigned char* dst = ws + (size_t)t * WTILE;
#pragma unroll
  for (int kc = 0; kc < 4; ++kc) {
    float v[8];
    float4 a = ((const float4*)src)[kc * 2];
    float4 b = ((const float4*)src)[kc * 2 + 1];
    v[0] = a.x * SW; v[1] = a.y * SW; v[2] = a.z * SW; v[3] = a.w * SW;
    v[4] = b.x * SW; v[5] = b.y * SW; v[6] = b.z * SW; v[7] = b.w * SW;
    half8 h, l;
    cvt8_2(v, h, l);
    int col = (kc * 16) ^ ((e & 6) << 3);
    *(half8*)(dst + e * 64 + col) = h;
    *(half8*)(dst + 16384 + e * 64 + col) = l;
  }
}

// ---------------------------------------------------------------------------
// K-split GEMM: BM=128, full N=256, A-only LDS, W reg-double-buffered from L2.
// Grid 256 = 128 M-tiles x 2 K-halves; khalf = g&1 -> even XCDs serve half 0,
// odd XCDs half 1. 512 thr = 8 waves (2m x 4n), wave tile 64x64.
// Steady state: W(t+1) and X(t+2) in flight; barrier waits lgkmcnt(0) only.
// ---------------------------------------------------------------------------
__global__ __launch_bounds__(512, 2) void gate_split_kernel(
    const float* __restrict__ X,
    const unsigned char* __restrict__ ws,
    float* __restrict__ part) {
  // LDS: A dbuf [2][16KB]; buf b at b*16384: hi plane [128 rows][64B], lo +8192.
  __shared__ unsigned char smem[32768] __attribute__((aligned(16)));

  const int g = blockIdx.x;
  const int khalf = g & 1;
  const int m0 = (g >> 1) * 128;

  const int tid = threadIdx.x;
  const int lane = tid & 63;
  const int wid = tid >> 6;  // 0..7
  const int wm = wid >> 2;   // 0..1: rows wm*64..+64
  const int wn = wid & 3;    // 0..3: experts wn*64..+64
  const int lr = lane & 15;
  const int lg = lane >> 4;

  // W per-lane byte offset in a step image; expert e = wn*64 + n*16 + lr has
  // e&6 == lr&6, so n folds into +n*1024.
  const unsigned char* img0 = ws + (size_t)khalf * KH * WTILE;
  const int wOff = (wn * 64 + lr) * 64 + ((lg * 16) ^ ((lr & 6) << 3));

  // A frag byte offsets (XOR-swizzled), m = 0..3 -> rows wm*64 + m*16 + lr
  int aOff[4];
#pragma unroll
  for (int m = 0; m < 4; ++m) {
    int r = wm * 64 + m * 16 + lr;
    aOff[m] = r * 64 + ((lg * 16) ^ ((r & 6) << 3));
  }

  // X staging: 512 threads cover 128 rows x 4 chunks of 8 floats
  const int xr = tid >> 2;
  const int xkc = tid & 3;
  const float* xsrc = X + (size_t)(m0 + xr) * K_DIM + (size_t)khalf * KH * BK + xkc * 8;
  const int xcol = (xkc * 16) ^ ((xr & 6) << 3);

  auto load_w = [&](int t, half8 (&wh)[4], half8 (&wl)[4]) {
    const unsigned char* wp = img0 + (size_t)t * WTILE + wOff;
#pragma unroll
    for (int n = 0; n < 4; ++n) wh[n] = *(const half8*)(wp + n * 1024);
#pragma unroll
    for (int n = 0; n < 4; ++n) wl[n] = *(const half8*)(wp + 16384 + n * 1024);
  };
  auto load_x = [&](int t, f32x4& x0, f32x4& x1) {
    x0 = __builtin_nontemporal_load((const f32x4*)(xsrc + (size_t)t * BK));
    x1 = __builtin_nontemporal_load((const f32x4*)(xsrc + (size_t)t * BK + 4));
  };
  auto write_x = [&](int b, const f32x4& x0, const f32x4& x1) {
    float v[8] = {x0[0] * SX, x0[1] * SX, x0[2] * SX, x0[3] * SX,
                  x1[0] * SX, x1[1] * SX, x1[2] * SX, x1[3] * SX};
    half8 h, l;
    cvt8_2(v, h, l);
    unsigned char* Ab = smem + b * 16384;
    *(half8*)(Ab + xr * 64 + xcol) = h;
    *(half8*)(Ab + 8192 + xr * 64 + xcol) = l;
  };

  f32x4 acc[4][4];   // xh*wh
  f32x4 accc[4][4];  // xl*wh + xh*wl
#pragma unroll
  for (int m = 0; m < 4; ++m)
#pragma unroll
    for (int n = 0; n < 4; ++n) {
      acc[m][n] = (f32x4){0.f, 0.f, 0.f, 0.f};
      accc[m][n] = (f32x4){0.f, 0.f, 0.f, 0.f};
    }

  half8 whA[4], wlA[4], whB[4], wlB[4];
  f32x4 xA0, xA1, xB0, xB1;

  // prologue: W(0)->setA issued first (oldest in FIFO), X(0) consumed into
  // A(0), X(1)->xA stays in flight.
  load_w(0, whA, wlA);
  {
    f32x4 t0, t1;
    load_x(0, t0, t1);
    write_x(0, t0, t1);  // compiler-counted wait on t0/t1 only
  }
  load_x(1, xA0, xA1);
  asm volatile("s_waitcnt lgkmcnt(0)" ::: "memory");
  __builtin_amdgcn_s_barrier();

  // One step: consumes W set "cur" (resident), prefetches W(t+1) into "nxt";
  // consumes X pair xcons (=X(t+1), in flight since last step), loads X(t+2)
  // into xload. Issue order: W first, X second (FIFO: no MFMA waits behind
  // an HBM load). sched_barrier pins the issue cluster at the top.
  auto body = [&](int t, half8 (&whC)[4], half8 (&wlC)[4],
                  half8 (&whN)[4], half8 (&wlN)[4],
                  f32x4& xl0, f32x4& xl1, const f32x4& xc0, const f32x4& xc1) {
    const int cur = t & 1;
    if (t + 1 < KH) load_w(t + 1, whN, wlN);
    if (t + 2 < KH) load_x(t + 2, xl0, xl1);
    __builtin_amdgcn_sched_barrier(0);

    const unsigned char* Ab = smem + cur * 16384;
#pragma unroll
    for (int m = 0; m < 4; ++m) {
      half8 xh = *(const half8*)(Ab + aOff[m]);
      half8 xl = *(const half8*)(Ab + 8192 + aOff[m]);
#pragma unroll
      for (int n = 0; n < 4; ++n) {
        acc[m][n] = __builtin_amdgcn_mfma_f32_16x16x32_f16(xh, whC[n], acc[m][n], 0, 0, 0);
        f32x4 c = accc[m][n];
        c = __builtin_amdgcn_mfma_f32_16x16x32_f16(xl, whC[n], c, 0, 0, 0);
        c = __builtin_amdgcn_mfma_f32_16x16x32_f16(xh, wlC[n], c, 0, 0, 0);
        accc[m][n] = c;
      }
    }

    if (t + 1 < KH) {
      write_x(cur ^ 1, xc0, xc1);  // counted vmcnt: only drains X(t+1)
      asm volatile("s_waitcnt lgkmcnt(0)" ::: "memory");
      __builtin_amdgcn_s_barrier();
    }
  };

#pragma clang loop unroll(disable)
  for (int t = 0; t < KH; t += 2) {
    body(t, whA, wlA, whB, wlB, xB0, xB1, xA0, xA1);      // even: cur=A
    body(t + 1, whB, wlB, whA, wlA, xA0, xA1, xB0, xB1);  // odd:  cur=B
  }

  // ---- epilogue: raw prescaled partial logits -> part[khalf]
  // (regular stores: partials stay L2/L3-resident for the reducer)
  float* dst = part + (size_t)khalf * P_ELEMS + (size_t)m0 * N_EXP;
#pragma unroll
  for (int m = 0; m < 4; ++m)
#pragma unroll
    for (int n = 0; n < 4; ++n)
#pragma unroll
      for (int r = 0; r < 4; ++r) {
        int row = wm * 64 + m * 16 + lg * 4 + r;
        int col = wn * 64 + n * 16 + lr;
        dst[(size_t)row * N_EXP + col] = acc[m][n][r] + accc[m][n][r];
      }
}

// ---------------------------------------------------------------------------
// Reducer: add the two K-half partials, descale, sigmoid, fused top-8.
// Grid 512 x 256 threads; block handles 32 rows.
// ---------------------------------------------------------------------------
__global__ __launch_bounds__(256) void reduce_topk_kernel(
    const float* __restrict__ part,
    const float* __restrict__ bias,
    float* __restrict__ out) {
  __shared__ float sc[32 * 260];

  const int tid = threadIdx.x;
  const int lane = tid & 63;
  const int wid = tid >> 6;
  const int r0 = blockIdx.x * 32;

  const float* p0 = part;
  const float* p1 = part + P_ELEMS;

  {
    int row = tid >> 3, seg = tid & 7;
    size_t base = (size_t)(r0 + row) * N_EXP + seg * 32;
#pragma unroll
    for (int j = 0; j < 8; ++j) {
      f32x4 a = *(const f32x4*)(p0 + base + j * 4);
      f32x4 b = *(const f32x4*)(p1 + base + j * 4);
#pragma unroll
      for (int e = 0; e < 4; ++e) {
        float v = (a[e] + b[e]) * DESCALE;
        sc[row * 260 + seg * 32 + j * 4 + e] = 1.0f / (1.0f + expf(-v));
      }
    }
  }
  __syncthreads();

  const float bb0 = bias[lane];
  const float bb1 = bias[lane + 64];
  const float bb2 = bias[lane + 128];
  const float bb3 = bias[lane + 192];
  const size_t TOT = (size_t)M_TOK * TOPK;

  for (int i = 0; i < 8; ++i) {
    int row = wid * 8 + i;
    float s0 = sc[row * 260 + lane];
    float s1 = sc[row * 260 + lane + 64];
    float s2 = sc[row * 260 + lane + 128];
    float s3 = sc[row * 260 + lane + 192];
    unsigned long long c0 = pack_ci(s0 + bb0, lane);
    unsigned long long c1 = pack_ci(s1 + bb1, lane + 64);
    unsigned long long c2 = pack_ci(s2 + bb2, lane + 128);
    unsigned long long c3 = pack_ci(s3 + bb3, lane + 192);
    float ssum = 0.f, my_s = 0.f;
    int my_idx = 0;
#pragma unroll
    for (int p = 0; p < TOPK; ++p) {
      unsigned long long b01 = c0 > c1 ? c0 : c1;
      unsigned long long b23 = c2 > c3 ? c2 : c3;
      unsigned long long best = b01 > b23 ? b01 : b23;
#pragma unroll
      for (int off = 1; off < 64; off <<= 1) {
        unsigned long long o = shflx64(best, off);
        if (o > best) best = o;
      }
      int idxw = 255 - (int)(best & 0xffull);
      int lw = idxw & 63;
      int jw = idxw >> 6;
      float sel = jw == 0 ? s0 : jw == 1 ? s1 : jw == 2 ? s2 : s3;
      float sw = __shfl(sel, lw);
      ssum += sw;
      if (lane == p) { my_idx = idxw; my_s = sw; }
      if (lane == lw) {
        if (jw == 0) c0 = 0ull;
        else if (jw == 1) c1 = 0ull;
        else if (jw == 2) c2 = 0ull;
        else c3 = 0ull;
      }
    }
    if (lane < TOPK) {
      size_t rg = (size_t)(r0 + row);
      out[rg * TOPK + lane] = (float)my_idx;
      out[TOT + rg * TOPK + lane] = my_s * (2.5f / (ssum + 1e-20f));
    }
  }
}

// ---------------------------------------------------------------------------
// Fallback (ws too small): monolithic kernel, W from Wg with on-the-fly split.
// ---------------------------------------------------------------------------
__global__ __launch_bounds__(512, 2) void gate_mono_kernel(
    const float* __restrict__ X,
    const float* __restrict__ Wg,
    const float* __restrict__ bias,
    float* __restrict__ out) {
  __shared__ unsigned char smem[81920] __attribute__((aligned(16)));

  const int tid = threadIdx.x;
  const int lane = tid & 63;
  const int wid = tid >> 6;
  const int wm = wid >> 2;
  const int wn = wid & 3;
  const int lr = lane & 15;
  const int lg = lane >> 4;
  const int m0 = blockIdx.x * 64;

  int aOff[2], bOff[4];
#pragma unroll
  for (int m = 0; m < 2; ++m) {
    int r = wm * 32 + m * 16 + lr;
    aOff[m] = r * 64 + ((lg * 16) ^ ((r & 6) << 3));
  }
#pragma unroll
  for (int n = 0; n < 4; ++n) {
    int e = wn * 64 + n * 16 + lr;
    bOff[n] = e * 64 + ((lg * 16) ^ ((e & 6) << 3));
  }

  const int xr = tid >> 3;
  const int xkc = tid & 7;
  const float* xsrc = X + (size_t)(m0 + xr) * K_DIM + xkc * 4;
  const int xcol = (xkc * 8) ^ ((xr & 6) << 3);

  auto load_x = [&](int t, f32x4& dst) {
    dst = *(const f32x4*)(xsrc + (size_t)t * BK);
  };
  auto write_x = [&](int b, const f32x4& xv) {
    float v[4] = {xv[0] * SX, xv[1] * SX, xv[2] * SX, xv[3] * SX};
    half4 h, l;
    cvt4_2(v, h, l);
    unsigned char* Ab = smem + b * 8192;
    *(half4*)(Ab + xr * 64 + xcol) = h;
    *(half4*)(Ab + 4096 + xr * 64 + xcol) = l;
  };
  auto stage_w = [&](int t, int b) {
    unsigned char* Bb = smem + 16384 + b * 32768;
    int row = tid >> 1;
    int g0 = (tid & 1) * 2;
    const float* src = Wg + (size_t)row * K_DIM + (size_t)t * BK + g0 * 8;
#pragma unroll
    for (int g = 0; g < 2; ++g) {
      float v[8];
      float4 a = ((const float4*)src)[g * 2];
      float4 bq = ((const float4*)src)[g * 2 + 1];
      v[0] = a.x * SW; v[1] = a.y * SW; v[2] = a.z * SW; v[3] = a.w * SW;
      v[4] = bq.x * SW; v[5] = bq.y * SW; v[6] = bq.z * SW; v[7] = bq.w * SW;
      half8 h, l;
      cvt8_2(v, h, l);
      int col = ((g0 + g) * 16) ^ ((row & 6) << 3);
      *(half8*)(Bb + row * 64 + col) = h;
      *(half8*)(Bb + 16384 + row * 64 + col) = l;
    }
  };

  f32x4 acc[2][4], accc[2][4];
#pragma unroll
  for (int m = 0; m < 2; ++m)
#pragma unroll
    for (int n = 0; n < 4; ++n) {
      acc[m][n] = (f32x4){0.f, 0.f, 0.f, 0.f};
      accc[m][n] = (f32x4){0.f, 0.f, 0.f, 0.f};
    }

  f32x4 xqA, xqB;
  stage_w(0, 0);
  load_x(0, xqA);
  write_x(0, xqA);
  load_x(1, xqB);
  __syncthreads();

#pragma clang loop unroll(disable)
  for (int t = 0; t < KSTEPS; ++t) {
    const int cur = t & 1, nxt = cur ^ 1;
    f32x4& xload = (t & 1) ? xqB : xqA;
    const f32x4& xcons = (t & 1) ? xqA : xqB;
    if (t + 1 < KSTEPS) stage_w(t + 1, nxt);
    if (t + 2 < KSTEPS) load_x(t + 2, xload);

    const unsigned char* Ab = smem + cur * 8192;
    const unsigned char* Bb = smem + 16384 + cur * 32768;
    half8 xh[2], xl[2], wh[4], wl[4];
#pragma unroll
    for (int m = 0; m < 2; ++m) {
      xh[m] = *(const half8*)(Ab + aOff[m]);
      xl[m] = *(const half8*)(Ab + 4096 + aOff[m]);
    }
#pragma unroll
    for (int n = 0; n < 4; ++n) {
      wh[n] = *(const half8*)(Bb + bOff[n]);
      wl[n] = *(const half8*)(Bb + 16384 + bOff[n]);
    }
#pragma unroll
    for (int m = 0; m < 2; ++m)
#pragma unroll
      for (int n = 0; n < 4; ++n) {
        acc[m][n] = __builtin_amdgcn_mfma_f32_16x16x32_f16(xh[m], wh[n], acc[m][n], 0, 0, 0);
        f32x4 c = accc[m][n];
        c = __builtin_amdgcn_mfma_f32_16x16x32_f16(xh[m], wl[n], c, 0, 0, 0);
        c = __builtin_amdgcn_mfma_f32_16x16x32_f16(xl[m], wh[n], c, 0, 0, 0);
        accc[m][n] = c;
      }
    if (t + 1 < KSTEPS) {
      write_x(nxt, xcons);
      __syncthreads();
    }
  }
  __syncthreads();

  float* sc = (float*)smem;
#pragma unroll
  for (int m = 0; m < 2; ++m)
#pragma unroll
    for (int n = 0; n < 4; ++n)
#pragma unroll
      for (int r = 0; r < 4; ++r) {
        int row = wm * 32 + m * 16 + lg * 4 + r;
        int col = wn * 64 + n * 16 + lr;
        float v = (acc[m][n][r] + accc[m][n][r]) * DESCALE;
        sc[row * 260 + col] = 1.0f / (1.0f + expf(-v));
      }
  __syncthreads();

  const float bb0 = bias[lane];
  const float bb1 = bias[lane + 64];
  const float bb2 = bias[lane + 128];
  const float bb3 = bias[lane + 192];
  const size_t TOT = (size_t)M_TOK * TOPK;

  for (int i = 0; i < 8; ++i) {
    int row = wid * 8 + i;
    float s0 = sc[row * 260 + lane];
    float s1 = sc[row * 260 + lane + 64];
    float s2 = sc[row * 260 + lane + 128];
    float s3 = sc[row * 260 + lane + 192];
    unsigned long long c0 = pack_ci(s0 + bb0, lane);
    unsigned long long c1 = pack_ci(s1 + bb1, lane + 64);
    unsigned long long c2 = pack_ci(s2 + bb2, lane + 128);
    unsigned long long c3 = pack_ci(s3 + bb3, lane + 192);
    float ssum = 0.f, my_s = 0.f;
    int my_idx = 0;
#pragma unroll
    for (int p = 0; p < TOPK; ++p) {
      unsigned long long b01 = c0 > c1 ? c0 : c1;
      unsigned long long b23 = c2 > c3 ? c2 : c3;
      unsigned long long best = b01 > b23 ? b01 : b23;
#pragma unroll
      for (int off = 1; off < 64; off <<= 1) {
        unsigned long long o = shflx64(best, off);
        if (o > best) best = o;
      }
      int idxw = 255 - (int)(best & 0xffull);
      int lw = idxw & 63;
      int jw = idxw >> 6;
      float sel = jw == 0 ? s0 : jw == 1 ? s1 : jw == 2 ? s2 : s3;
      float sw = __shfl(sel, lw);
      ssum += sw;
      if (lane == p) { my_idx = idxw; my_s = sw; }
      if (lane == lw) {
        if (jw == 0) c0 = 0ull;
        else if (jw == 1) c1 = 0ull;
        else if (jw == 2) c2 = 0ull;
        else c3 = 0ull;
      }
    }
    if (lane < TOPK) {
      size_t rg = (size_t)(m0 + row);
      out[rg * TOPK + lane] = (float)my_idx;
      out[TOT + rg * TOPK + lane] = my_s * (2.5f / (ssum + 1e-20f));
    }
  }
}

extern "C" void kernel_launch(void* const* d_in, const int* in_sizes, int n_in,
                              void* d_out, int out_size, void* d_ws, size_t ws_size,
                              hipStream_t stream) {
  const float* X = (const float*)d_in[0];
  const float* W = (const float*)d_in[1];
  const float* bias = (const float*)d_in[2];
  float* out = (float*)d_out;

  const size_t need = IMG_BYTES + 2 * P_ELEMS * sizeof(float);  // ~40.9 MB
  if (d_ws != nullptr && ws_size >= need) {
    unsigned char* ws = (unsigned char*)d_ws;
    float* part = (float*)(ws + IMG_BYTES);
    prep_w_kernel<<<KSTEPS, 256, 0, stream>>>(W, ws);
    gate_split_kernel<<<2 * (M_TOK / 128), 512, 0, stream>>>(X, ws, part);
    reduce_topk_kernel<<<M_TOK / 32, 256, 0, stream>>>(part, bias, out);
  } else {
    gate_mono_kernel<<<M_TOK / 64, 512, 0, stream>>>(X, W, bias, out);
  }
}

// Round 13
// 225.773 us; speedup vs baseline: 1.3866x; 1.1639x over previous
//
#include <hip/hip_runtime.h>
#include <hip/hip_bf16.h>
#include <math.h>

#define M_TOK 16384
#define N_EXP 256
#define K_DIM 7168
#define BK 32
#define KSTEPS (K_DIM / BK)  /* 224 */
#define KH (KSTEPS / 2)      /* 112 steps per K-half */
#define WTILE 32768          /* bytes per k-step W image: 16KB hi + 16KB lo (fp16) */
#define IMG_BYTES ((size_t)KSTEPS * WTILE)  /* 7.34 MB */
#define P_ELEMS ((size_t)M_TOK * N_EXP)
#define TOPK 8
#define SX 4096.0f
#define SW 16384.0f
#define DESCALE 1.4901161193847656e-08f /* 2^-26 */

typedef __attribute__((ext_vector_type(8))) _Float16 half8;
typedef __attribute__((ext_vector_type(4))) _Float16 half4;
typedef __attribute__((ext_vector_type(4))) float f32x4;

__device__ __forceinline__ void cvt8_2(const float* v, half8& h, half8& l) {
#pragma unroll
  for (int i = 0; i < 8; ++i) {
    _Float16 a = (_Float16)v[i];
    float r = v[i] - (float)a;
    h[i] = a;
    l[i] = (_Float16)r;
  }
}
__device__ __forceinline__ void cvt4_2(const float* v, half4& h, half4& l) {
#pragma unroll
  for (int i = 0; i < 4; ++i) {
    _Float16 a = (_Float16)v[i];
    float r = v[i] - (float)a;
    h[i] = a;
    l[i] = (_Float16)r;
  }
}

__device__ __forceinline__ unsigned long long pack_ci(float key, int idx) {
  unsigned int u = __builtin_bit_cast(unsigned int, key);
  u = (u & 0x80000000u) ? ~u : (u | 0x80000000u);
  return ((unsigned long long)u << 32) | (unsigned)(255 - idx);
}
__device__ __forceinline__ unsigned long long shflx64(unsigned long long v, int off) {
  int lo = __shfl_xor((int)(unsigned)(v & 0xffffffffull), off);
  int hi = __shfl_xor((int)(unsigned)(v >> 32), off);
  return ((unsigned long long)(unsigned)hi << 32) | (unsigned)lo;
}

// gate_weight fp32 [256][7168] -> per-kstep swizzled fp16 images in ws.
// Image t (32KB): hi plane [256 rows][64B] at +0, lo plane at +16384.
// byte col of 16B granule kc: (kc*16) ^ ((e&6)<<3).
__global__ void prep_w_kernel(const float* __restrict__ W, unsigned char* __restrict__ ws) {
  int t = blockIdx.x;
  int e = threadIdx.x;
  const float* src = W + (size_t)e * K_DIM + t * BK;
  unsigned char* dst = ws + (size_t)t * WTILE;
#pragma unroll
  for (int kc = 0; kc < 4; ++kc) {
    float v[8];
    float4 a = ((const float4*)src)[kc * 2];
    float4 b = ((const float4*)src)[kc * 2 + 1];
    v[0] = a.x * SW; v[1] = a.y * SW; v[2] = a.z * SW; v[3] = a.w * SW;
    v[4] = b.x * SW; v[5] = b.y * SW; v[6] = b.z * SW; v[7] = b.w * SW;
    half8 h, l;
    cvt8_2(v, h, l);
    int col = (kc * 16) ^ ((e & 6) << 3);
    *(half8*)(dst + e * 64 + col) = h;
    *(half8*)(dst + 16384 + e * 64 + col) = l;
  }
}

// ---------------------------------------------------------------------------
// K-split GEMM, high-occupancy variant: BM=64, 8 waves each owning the full
// 64 rows x a DISTINCT 32-expert slice (no W read duplication). A-only LDS
// (16KB/block). W single-buffered global(L2)->reg. acc+accc = 64 VGPR/wave
// -> fits 128-reg cap -> 2 blocks/CU, 16 waves/CU, two independent barrier
// domains. Grid 512 = 256 M-tiles x 2 K-halves; khalf=(g>>2)&1 gives XCDs
// 0-3 half 0, XCDs 4-7 half 1 (3.67MB half-image per XCD L2).
// ---------------------------------------------------------------------------
__global__ __launch_bounds__(512, 4) void gate_split_kernel(
    const float* __restrict__ X,
    const unsigned char* __restrict__ ws,
    float* __restrict__ part) {
  // LDS: A dbuf [2][8KB]; buf b at b*8192: hi plane [64 rows][64B], lo +4096.
  __shared__ unsigned char smem[16384] __attribute__((aligned(16)));

  const int g = blockIdx.x;
  const int khalf = (g >> 2) & 1;
  const int mtile = ((g >> 3) << 2) | (g & 3);
  const int m0 = mtile * 64;

  const int tid = threadIdx.x;
  const int lane = tid & 63;
  const int wid = tid >> 6;  // 0..7: expert slice wid*32..+32
  const int lr = lane & 15;
  const int lg = lane >> 4;

  // W per-lane byte offset in a step image; expert e = wid*32 + n*16 + lr has
  // e&6 == lr&6 (bits 1-2 come only from lr), so n folds into +n*1024.
  const unsigned char* img0 = ws + (size_t)khalf * KH * WTILE;
  const int wOff = (wid * 32 + lr) * 64 + ((lg * 16) ^ ((lr & 6) << 3));

  // A frag byte offsets (XOR-swizzled), m = 0..3 -> rows m*16 + lr
  int aOff[4];
#pragma unroll
  for (int m = 0; m < 4; ++m) {
    int r = m * 16 + lr;
    aOff[m] = r * 64 + ((lg * 16) ^ ((r & 6) << 3));
  }

  // X staging: 512 threads cover 64 rows x 8 chunks of 4 floats
  const int xr = tid >> 3;
  const int xkc = tid & 7;
  const float* xsrc = X + (size_t)(m0 + xr) * K_DIM + (size_t)khalf * KH * BK + xkc * 4;
  const int xcol = (xkc * 8) ^ ((xr & 6) << 3);

  auto write_x = [&](int b, const f32x4& xv) {
    float v[4] = {xv[0] * SX, xv[1] * SX, xv[2] * SX, xv[3] * SX};
    half4 h, l;
    cvt4_2(v, h, l);
    unsigned char* Ab = smem + b * 8192;
    *(half4*)(Ab + xr * 64 + xcol) = h;
    *(half4*)(Ab + 4096 + xr * 64 + xcol) = l;
  };

  f32x4 acc[4][2];   // xh*wh
  f32x4 accc[4][2];  // xl*wh + xh*wl
#pragma unroll
  for (int m = 0; m < 4; ++m)
#pragma unroll
    for (int n = 0; n < 2; ++n) {
      acc[m][n] = (f32x4){0.f, 0.f, 0.f, 0.f};
      accc[m][n] = (f32x4){0.f, 0.f, 0.f, 0.f};
    }

  // prologue: A(0) into buf0
  {
    f32x4 x0 = __builtin_nontemporal_load((const f32x4*)xsrc);
    write_x(0, x0);
    asm volatile("s_waitcnt lgkmcnt(0)" ::: "memory");
    __builtin_amdgcn_s_barrier();
  }

#pragma clang loop unroll(disable)
  for (int t = 0; t < KH; ++t) {
    const int cur = t & 1;
    const bool hasNext = (t + 1 < KH);

    // W(t): 4 x 16B from L2 (issued FIRST -> FIFO head; MFMAs wait only
    // vmcnt(1), never behind the X HBM load)
    const unsigned char* wp = img0 + (size_t)t * WTILE + wOff;
    half8 wh0 = *(const half8*)(wp);
    half8 wh1 = *(const half8*)(wp + 1024);
    half8 wl0 = *(const half8*)(wp + 16384);
    half8 wl1 = *(const half8*)(wp + 16384 + 1024);

    // X(t+1): 1 x 16B HBM (in flight across this step's MFMAs)
    f32x4 xq;
    if (hasNext)
      xq = __builtin_nontemporal_load((const f32x4*)(xsrc + (size_t)(t + 1) * BK));
    __builtin_amdgcn_sched_barrier(0);

    const unsigned char* Ab = smem + cur * 8192;
#pragma unroll
    for (int m = 0; m < 4; ++m) {
      half8 xh = *(const half8*)(Ab + aOff[m]);
      half8 xl = *(const half8*)(Ab + 4096 + aOff[m]);
      acc[m][0] = __builtin_amdgcn_mfma_f32_16x16x32_f16(xh, wh0, acc[m][0], 0, 0, 0);
      f32x4 c0 = accc[m][0];
      c0 = __builtin_amdgcn_mfma_f32_16x16x32_f16(xl, wh0, c0, 0, 0, 0);
      c0 = __builtin_amdgcn_mfma_f32_16x16x32_f16(xh, wl0, c0, 0, 0, 0);
      accc[m][0] = c0;
      acc[m][1] = __builtin_amdgcn_mfma_f32_16x16x32_f16(xh, wh1, acc[m][1], 0, 0, 0);
      f32x4 c1 = accc[m][1];
      c1 = __builtin_amdgcn_mfma_f32_16x16x32_f16(xl, wh1, c1, 0, 0, 0);
      c1 = __builtin_amdgcn_mfma_f32_16x16x32_f16(xh, wl1, c1, 0, 0, 0);
      accc[m][1] = c1;
    }

    if (hasNext) {
      write_x(cur ^ 1, xq);  // counted vmcnt drains only xq
      asm volatile("s_waitcnt lgkmcnt(0)" ::: "memory");
      __builtin_amdgcn_s_barrier();
    }
  }

  // ---- epilogue: raw prescaled partial logits -> part[khalf]
  float* dst = part + (size_t)khalf * P_ELEMS + (size_t)m0 * N_EXP;
#pragma unroll
  for (int m = 0; m < 4; ++m)
#pragma unroll
    for (int n = 0; n < 2; ++n)
#pragma unroll
      for (int r = 0; r < 4; ++r) {
        int row = m * 16 + lg * 4 + r;
        int col = wid * 32 + n * 16 + lr;
        dst[(size_t)row * N_EXP + col] = acc[m][n][r] + accc[m][n][r];
      }
}

// ---------------------------------------------------------------------------
// Reducer: add the two K-half partials, descale, sigmoid, fused top-8.
// Grid 512 x 256 threads; block handles 32 rows.
// ---------------------------------------------------------------------------
__global__ __launch_bounds__(256) void reduce_topk_kernel(
    const float* __restrict__ part,
    const float* __restrict__ bias,
    float* __restrict__ out) {
  __shared__ float sc[32 * 260];

  const int tid = threadIdx.x;
  const int lane = tid & 63;
  const int wid = tid >> 6;
  const int r0 = blockIdx.x * 32;

  const float* p0 = part;
  const float* p1 = part + P_ELEMS;

  {
    int row = tid >> 3, seg = tid & 7;
    size_t base = (size_t)(r0 + row) * N_EXP + seg * 32;
#pragma unroll
    for (int j = 0; j < 8; ++j) {
      f32x4 a = *(const f32x4*)(p0 + base + j * 4);
      f32x4 b = *(const f32x4*)(p1 + base + j * 4);
#pragma unroll
      for (int e = 0; e < 4; ++e) {
        float v = (a[e] + b[e]) * DESCALE;
        sc[row * 260 + seg * 32 + j * 4 + e] = 1.0f / (1.0f + expf(-v));
      }
    }
  }
  __syncthreads();

  const float bb0 = bias[lane];
  const float bb1 = bias[lane + 64];
  const float bb2 = bias[lane + 128];
  const float bb3 = bias[lane + 192];
  const size_t TOT = (size_t)M_TOK * TOPK;

  for (int i = 0; i < 8; ++i) {
    int row = wid * 8 + i;
    float s0 = sc[row * 260 + lane];
    float s1 = sc[row * 260 + lane + 64];
    float s2 = sc[row * 260 + lane + 128];
    float s3 = sc[row * 260 + lane + 192];
    unsigned long long c0 = pack_ci(s0 + bb0, lane);
    unsigned long long c1 = pack_ci(s1 + bb1, lane + 64);
    unsigned long long c2 = pack_ci(s2 + bb2, lane + 128);
    unsigned long long c3 = pack_ci(s3 + bb3, lane + 192);
    float ssum = 0.f, my_s = 0.f;
    int my_idx = 0;
#pragma unroll
    for (int p = 0; p < TOPK; ++p) {
      unsigned long long b01 = c0 > c1 ? c0 : c1;
      unsigned long long b23 = c2 > c3 ? c2 : c3;
      unsigned long long best = b01 > b23 ? b01 : b23;
#pragma unroll
      for (int off = 1; off < 64; off <<= 1) {
        unsigned long long o = shflx64(best, off);
        if (o > best) best = o;
      }
      int idxw = 255 - (int)(best & 0xffull);
      int lw = idxw & 63;
      int jw = idxw >> 6;
      float sel = jw == 0 ? s0 : jw == 1 ? s1 : jw == 2 ? s2 : s3;
      float sw = __shfl(sel, lw);
      ssum += sw;
      if (lane == p) { my_idx = idxw; my_s = sw; }
      if (lane == lw) {
        if (jw == 0) c0 = 0ull;
        else if (jw == 1) c1 = 0ull;
        else if (jw == 2) c2 = 0ull;
        else c3 = 0ull;
      }
    }
    if (lane < TOPK) {
      size_t rg = (size_t)(r0 + row);
      out[rg * TOPK + lane] = (float)my_idx;
      out[TOT + rg * TOPK + lane] = my_s * (2.5f / (ssum + 1e-20f));
    }
  }
}

// ---------------------------------------------------------------------------
// Fallback (ws too small): monolithic kernel, W from Wg with on-the-fly split.
// ---------------------------------------------------------------------------
__global__ __launch_bounds__(512, 2) void gate_mono_kernel(
    const float* __restrict__ X,
    const float* __restrict__ Wg,
    const float* __restrict__ bias,
    float* __restrict__ out) {
  __shared__ unsigned char smem[81920] __attribute__((aligned(16)));

  const int tid = threadIdx.x;
  const int lane = tid & 63;
  const int wid = tid >> 6;
  const int wm = wid >> 2;
  const int wn = wid & 3;
  const int lr = lane & 15;
  const int lg = lane >> 4;
  const int m0 = blockIdx.x * 64;

  int aOff[2], bOff[4];
#pragma unroll
  for (int m = 0; m < 2; ++m) {
    int r = wm * 32 + m * 16 + lr;
    aOff[m] = r * 64 + ((lg * 16) ^ ((r & 6) << 3));
  }
#pragma unroll
  for (int n = 0; n < 4; ++n) {
    int e = wn * 64 + n * 16 + lr;
    bOff[n] = e * 64 + ((lg * 16) ^ ((e & 6) << 3));
  }

  const int xr = tid >> 3;
  const int xkc = tid & 7;
  const float* xsrc = X + (size_t)(m0 + xr) * K_DIM + xkc * 4;
  const int xcol = (xkc * 8) ^ ((xr & 6) << 3);

  auto load_x = [&](int t, f32x4& dst) {
    dst = *(const f32x4*)(xsrc + (size_t)t * BK);
  };
  auto write_x = [&](int b, const f32x4& xv) {
    float v[4] = {xv[0] * SX, xv[1] * SX, xv[2] * SX, xv[3] * SX};
    half4 h, l;
    cvt4_2(v, h, l);
    unsigned char* Ab = smem + b * 8192;
    *(half4*)(Ab + xr * 64 + xcol) = h;
    *(half4*)(Ab + 4096 + xr * 64 + xcol) = l;
  };
  auto stage_w = [&](int t, int b) {
    unsigned char* Bb = smem + 16384 + b * 32768;
    int row = tid >> 1;
    int g0 = (tid & 1) * 2;
    const float* src = Wg + (size_t)row * K_DIM + (size_t)t * BK + g0 * 8;
#pragma unroll
    for (int g = 0; g < 2; ++g) {
      float v[8];
      float4 a = ((const float4*)src)[g * 2];
      float4 bq = ((const float4*)src)[g * 2 + 1];
      v[0] = a.x * SW; v[1] = a.y * SW; v[2] = a.z * SW; v[3] = a.w * SW;
      v[4] = bq.x * SW; v[5] = bq.y * SW; v[6] = bq.z * SW; v[7] = bq.w * SW;
      half8 h, l;
      cvt8_2(v, h, l);
      int col = ((g0 + g) * 16) ^ ((row & 6) << 3);
      *(half8*)(Bb + row * 64 + col) = h;
      *(half8*)(Bb + 16384 + row * 64 + col) = l;
    }
  };

  f32x4 acc[2][4], accc[2][4];
#pragma unroll
  for (int m = 0; m < 2; ++m)
#pragma unroll
    for (int n = 0; n < 4; ++n) {
      acc[m][n] = (f32x4){0.f, 0.f, 0.f, 0.f};
      accc[m][n] = (f32x4){0.f, 0.f, 0.f, 0.f};
    }

  f32x4 xqA, xqB;
  stage_w(0, 0);
  load_x(0, xqA);
  write_x(0, xqA);
  load_x(1, xqB);
  __syncthreads();

#pragma clang loop unroll(disable)
  for (int t = 0; t < KSTEPS; ++t) {
    const int cur = t & 1, nxt = cur ^ 1;
    f32x4& xload = (t & 1) ? xqB : xqA;
    const f32x4& xcons = (t & 1) ? xqA : xqB;
    if (t + 1 < KSTEPS) stage_w(t + 1, nxt);
    if (t + 2 < KSTEPS) load_x(t + 2, xload);

    const unsigned char* Ab = smem + cur * 8192;
    const unsigned char* Bb = smem + 16384 + cur * 32768;
    half8 xh[2], xl[2], wh[4], wl[4];
#pragma unroll
    for (int m = 0; m < 2; ++m) {
      xh[m] = *(const half8*)(Ab + aOff[m]);
      xl[m] = *(const half8*)(Ab + 4096 + aOff[m]);
    }
#pragma unroll
    for (int n = 0; n < 4; ++n) {
      wh[n] = *(const half8*)(Bb + bOff[n]);
      wl[n] = *(const half8*)(Bb + 16384 + bOff[n]);
    }
#pragma unroll
    for (int m = 0; m < 2; ++m)
#pragma unroll
      for (int n = 0; n < 4; ++n) {
        acc[m][n] = __builtin_amdgcn_mfma_f32_16x16x32_f16(xh[m], wh[n], acc[m][n], 0, 0, 0);
        f32x4 c = accc[m][n];
        c = __builtin_amdgcn_mfma_f32_16x16x32_f16(xh[m], wl[n], c, 0, 0, 0);
        c = __builtin_amdgcn_mfma_f32_16x16x32_f16(xl[m], wh[n], c, 0, 0, 0);
        accc[m][n] = c;
      }
    if (t + 1 < KSTEPS) {
      write_x(nxt, xcons);
      __syncthreads();
    }
  }
  __syncthreads();

  float* sc = (float*)smem;
#pragma unroll
  for (int m = 0; m < 2; ++m)
#pragma unroll
    for (int n = 0; n < 4; ++n)
#pragma unroll
      for (int r = 0; r < 4; ++r) {
        int row = wm * 32 + m * 16 + lg * 4 + r;
        int col = wn * 64 + n * 16 + lr;
        float v = (acc[m][n][r] + accc[m][n][r]) * DESCALE;
        sc[row * 260 + col] = 1.0f / (1.0f + expf(-v));
      }
  __syncthreads();

  const float bb0 = bias[lane];
  const float bb1 = bias[lane + 64];
  const float bb2 = bias[lane + 128];
  const float bb3 = bias[lane + 192];
  const size_t TOT = (size_t)M_TOK * TOPK;

  for (int i = 0; i < 8; ++i) {
    int row = wid * 8 + i;
    float s0 = sc[row * 260 + lane];
    float s1 = sc[row * 260 + lane + 64];
    float s2 = sc[row * 260 + lane + 128];
    float s3 = sc[row * 260 + lane + 192];
    unsigned long long c0 = pack_ci(s0 + bb0, lane);
    unsigned long long c1 = pack_ci(s1 + bb1, lane + 64);
    unsigned long long c2 = pack_ci(s2 + bb2, lane + 128);
    unsigned long long c3 = pack_ci(s3 + bb3, lane + 192);
    float ssum = 0.f, my_s = 0.f;
    int my_idx = 0;
#pragma unroll
    for (int p = 0; p < TOPK; ++p) {
      unsigned long long b01 = c0 > c1 ? c0 : c1;
      unsigned long long b23 = c2 > c3 ? c2 : c3;
      unsigned long long best = b01 > b23 ? b01 : b23;
#pragma unroll
      for (int off = 1; off < 64; off <<= 1) {
        unsigned long long o = shflx64(best, off);
        if (o > best) best = o;
      }
      int idxw = 255 - (int)(best & 0xffull);
      int lw = idxw & 63;
      int jw = idxw >> 6;
      float sel = jw == 0 ? s0 : jw == 1 ? s1 : jw == 2 ? s2 : s3;
      float sw = __shfl(sel, lw);
      ssum += sw;
      if (lane == p) { my_idx = idxw; my_s = sw; }
      if (lane == lw) {
        if (jw == 0) c0 = 0ull;
        else if (jw == 1) c1 = 0ull;
        else if (jw == 2) c2 = 0ull;
        else c3 = 0ull;
      }
    }
    if (lane < TOPK) {
      size_t rg = (size_t)(m0 + row);
      out[rg * TOPK + lane] = (float)my_idx;
      out[TOT + rg * TOPK + lane] = my_s * (2.5f / (ssum + 1e-20f));
    }
  }
}

extern "C" void kernel_launch(void* const* d_in, const int* in_sizes, int n_in,
                              void* d_out, int out_size, void* d_ws, size_t ws_size,
                              hipStream_t stream) {
  const float* X = (const float*)d_in[0];
  const float* W = (const float*)d_in[1];
  const float* bias = (const float*)d_in[2];
  float* out = (float*)d_out;

  const size_t need = IMG_BYTES + 2 * P_ELEMS * sizeof(float);  // ~40.9 MB
  if (d_ws != nullptr && ws_size >= need) {
    unsigned char* ws = (unsigned char*)d_ws;
    float* part = (float*)(ws + IMG_BYTES);
    prep_w_kernel<<<KSTEPS, 256, 0, stream>>>(W, ws);
    gate_split_kernel<<<2 * (M_TOK / 64), 512, 0, stream>>>(X, ws, part);
    reduce_topk_kernel<<<M_TOK / 32, 256, 0, stream>>>(part, bias, out);
  } else {
    gate_mono_kernel<<<M_TOK / 64, 512, 0, stream>>>(X, W, bias, out);
  }
}